// Round 1
// baseline (329.330 us; speedup 1.0000x reference)
//
#include <hip/hip_runtime.h>
#include <hip/hip_bf16.h>

#define BATCH 16384
#define NFIELDS 26
#define FIELD_DIM 100000
#define BASED 64

// One wave (64 lanes) per output row. lane == output dim d.
// Block0 (fields 0..7, dim 64):  direct coalesced gather-sum into acc[d].
// Block1 (fields 8..15, dim 32): gather-sum s1[lane&31] (replicated in both
//   wave halves), then project: acc[d] += sum_k s1[k] * W1[d][k].
// Block2 (fields 16..25, dim 16): same with lane&15 and W2.
// Projection is linear -> sum embeddings first, project once per row.
// Bias: each of nb field-projections adds +b, so acc += 8*b1[d] + 10*b2[d].

__global__ __launch_bounds__(256) void mixdim_embbag_kernel(
    const int* __restrict__ x,
    const float* __restrict__ t0,
    const float* __restrict__ t1,
    const float* __restrict__ t2,
    const float* __restrict__ W1,
    const float* __restrict__ b1,
    const float* __restrict__ W2,
    const float* __restrict__ b2,
    float* __restrict__ out)
{
    const int lane = threadIdx.x & 63;
    const int wave = threadIdx.x >> 6;
    const int row  = blockIdx.x * 4 + wave;
    if (row >= BATCH) return;

    // Preload projector rows into registers (fully-unrolled indexing keeps
    // them in VGPRs). W1 is (64,32) row-major; W2 is (64,16).
    float w1r[32];
    {
        const float4* W1v = (const float4*)(W1 + lane * 32);
        #pragma unroll
        for (int i = 0; i < 8; ++i) {
            float4 v = W1v[i];
            w1r[4*i+0] = v.x; w1r[4*i+1] = v.y; w1r[4*i+2] = v.z; w1r[4*i+3] = v.w;
        }
    }
    float w2r[16];
    {
        const float4* W2v = (const float4*)(W2 + lane * 16);
        #pragma unroll
        for (int i = 0; i < 4; ++i) {
            float4 v = W2v[i];
            w2r[4*i+0] = v.x; w2r[4*i+1] = v.y; w2r[4*i+2] = v.z; w2r[4*i+3] = v.w;
        }
    }

    // Load this row's 26 indices: lane f (<26) holds x[row][f]; broadcast by shuffle.
    int xi = 0;
    if (lane < NFIELDS) xi = x[row * NFIELDS + lane];

    // ---- block 0: fields 0..7, dim 64, identity projector ----
    float acc = 0.f;
    #pragma unroll
    for (int f = 0; f < 8; ++f) {
        const int r = __shfl(xi, f) + f * FIELD_DIM;   // row in t0
        acc += t0[r * 64 + lane];                      // 256 B coalesced
    }

    // ---- block 1: fields 8..15, dim 32 ----
    float s1 = 0.f;
    {
        const int d1 = lane & 31;
        #pragma unroll
        for (int f = 0; f < 8; ++f) {
            const int r = __shfl(xi, 8 + f) + f * FIELD_DIM; // row in t1
            s1 += t1[r * 32 + d1];                           // 128 B, halves duplicated
        }
    }
    // project: acc[d] += sum_k s1[k] * W1[d][k]
    #pragma unroll
    for (int k = 0; k < 32; ++k)
        acc += __shfl(s1, k) * w1r[k];

    // ---- block 2: fields 16..25, dim 16 ----
    float s2 = 0.f;
    {
        const int d2 = lane & 15;
        #pragma unroll
        for (int f = 0; f < 10; ++f) {
            const int r = __shfl(xi, 16 + f) + f * FIELD_DIM; // row in t2
            s2 += t2[r * 16 + d2];                            // 64 B, quarters duplicated
        }
    }
    #pragma unroll
    for (int k = 0; k < 16; ++k)
        acc += __shfl(s2, k) * w2r[k];

    // bias: 8 field-projections in block1, 10 in block2
    acc += 8.0f * b1[lane] + 10.0f * b2[lane];

    out[row * 64 + lane] = acc;
}

extern "C" void kernel_launch(void* const* d_in, const int* in_sizes, int n_in,
                              void* d_out, int out_size, void* d_ws, size_t ws_size,
                              hipStream_t stream) {
    const int*   x  = (const int*)  d_in[0];
    const float* t0 = (const float*)d_in[1];
    const float* t1 = (const float*)d_in[2];
    const float* t2 = (const float*)d_in[3];
    const float* W1 = (const float*)d_in[4];
    const float* b1 = (const float*)d_in[5];
    const float* W2 = (const float*)d_in[6];
    const float* b2 = (const float*)d_in[7];
    float* out = (float*)d_out;

    dim3 grid(BATCH / 4);   // 4 waves (rows) per 256-thread block
    dim3 block(256);
    hipLaunchKernelGGL(mixdim_embbag_kernel, grid, block, 0, stream,
                       x, t0, t1, t2, W1, b1, W2, b2, out);
}

// Round 2
// 325.082 us; speedup vs baseline: 1.0131x; 1.0131x over previous
//
#include <hip/hip_runtime.h>
#include <hip/hip_bf16.h>

#define BATCH 16384
#define NFIELDS 26
#define FIELD_DIM 100000
#define BASED 64

// One wave (64 lanes) handles TWO output rows. lane == output dim d.
//   lanes 0-31 carry row0's x-indices, lanes 32-63 carry row1's.
// Block0 (fields 0..7, dim 64):  direct coalesced gather-sum into acc[d].
// Block1 (fields 8..15, dim 32): gather-sum s1[lane&31] (replicated halves),
//   then project via shuffle-broadcast against register-resident W1 row.
// Block2 (fields 16..25, dim 16): same with lane&15 and W2.
// Projection is linear -> sum embeddings first, project once per row.
// Bias enters as 8*b1[d] + 10*b2[d].
// Gathers are nontemporal: tables (371 MB) have zero reuse; keep L2/L3 for
// x / W / bias.

__device__ __forceinline__ float ntload(const float* p) {
    return __builtin_nontemporal_load(p);
}

__global__ __launch_bounds__(256, 4) void mixdim_embbag_kernel(
    const int* __restrict__ x,
    const float* __restrict__ t0,
    const float* __restrict__ t1,
    const float* __restrict__ t2,
    const float* __restrict__ W1,
    const float* __restrict__ b1,
    const float* __restrict__ W2,
    const float* __restrict__ b2,
    float* __restrict__ out)
{
    const int lane = threadIdx.x & 63;
    const int wave = threadIdx.x >> 6;
    const int row0 = (blockIdx.x * 4 + wave) * 2;   // this wave's first row

    // Preload projector rows into registers. W1 is (64,32); W2 is (64,16).
    float w1r[32];
    {
        const float4* W1v = (const float4*)(W1 + lane * 32);
        #pragma unroll
        for (int i = 0; i < 8; ++i) {
            float4 v = W1v[i];
            w1r[4*i+0] = v.x; w1r[4*i+1] = v.y; w1r[4*i+2] = v.z; w1r[4*i+3] = v.w;
        }
    }
    float w2r[16];
    {
        const float4* W2v = (const float4*)(W2 + lane * 16);
        #pragma unroll
        for (int i = 0; i < 4; ++i) {
            float4 v = W2v[i];
            w2r[4*i+0] = v.x; w2r[4*i+1] = v.y; w2r[4*i+2] = v.z; w2r[4*i+3] = v.w;
        }
    }

    // Indices: lanes 0-25 hold row0's 26 fields, lanes 32-57 hold row1's.
    int xi = 0;
    {
        const int l = lane & 31;
        const int r = row0 + (lane >> 5);
        if (l < NFIELDS) xi = x[r * NFIELDS + l];
    }
    // row0 field f -> __shfl(xi, f); row1 field f -> __shfl(xi, 32+f)

    float acc0 = 0.f, acc1 = 0.f;

    // ---- block 0: fields 0..7, dim 64, identity projector ----
    #pragma unroll
    for (int f = 0; f < 8; ++f) {
        const int i0 = __shfl(xi, f)      + f * FIELD_DIM;
        const int i1 = __shfl(xi, 32 + f) + f * FIELD_DIM;
        acc0 += ntload(t0 + i0 * 64 + lane);
        acc1 += ntload(t0 + i1 * 64 + lane);
    }

    // ---- block 1: fields 8..15, dim 32 ----
    float s1_0 = 0.f, s1_1 = 0.f;
    {
        const int d1 = lane & 31;
        #pragma unroll
        for (int j = 0; j < 8; ++j) {
            const int i0 = __shfl(xi, 8 + j)      + j * FIELD_DIM;
            const int i1 = __shfl(xi, 32 + 8 + j) + j * FIELD_DIM;
            s1_0 += ntload(t1 + i0 * 32 + d1);
            s1_1 += ntload(t1 + i1 * 32 + d1);
        }
    }

    // ---- block 2: fields 16..25, dim 16 ----
    float s2_0 = 0.f, s2_1 = 0.f;
    {
        const int d2 = lane & 15;
        #pragma unroll
        for (int j = 0; j < 10; ++j) {
            const int i0 = __shfl(xi, 16 + j)      + j * FIELD_DIM;
            const int i1 = __shfl(xi, 32 + 16 + j) + j * FIELD_DIM;
            s2_0 += ntload(t2 + i0 * 16 + d2);
            s2_1 += ntload(t2 + i1 * 16 + d2);
        }
    }

    // ---- projections: acc[d] += sum_k s[k] * W[d][k] ----
    #pragma unroll
    for (int k = 0; k < 32; ++k) {
        const float w = w1r[k];
        acc0 += __shfl(s1_0, k) * w;
        acc1 += __shfl(s1_1, k) * w;
    }
    #pragma unroll
    for (int k = 0; k < 16; ++k) {
        const float w = w2r[k];
        acc0 += __shfl(s2_0, k) * w;
        acc1 += __shfl(s2_1, k) * w;
    }

    // bias: 8 field-projections in block1, 10 in block2
    const float bias = 8.0f * b1[lane] + 10.0f * b2[lane];
    acc0 += bias;
    acc1 += bias;

    out[row0 * 64 + lane]       = acc0;
    out[(row0 + 1) * 64 + lane] = acc1;
}

extern "C" void kernel_launch(void* const* d_in, const int* in_sizes, int n_in,
                              void* d_out, int out_size, void* d_ws, size_t ws_size,
                              hipStream_t stream) {
    const int*   x  = (const int*)  d_in[0];
    const float* t0 = (const float*)d_in[1];
    const float* t1 = (const float*)d_in[2];
    const float* t2 = (const float*)d_in[3];
    const float* W1 = (const float*)d_in[4];
    const float* b1 = (const float*)d_in[5];
    const float* W2 = (const float*)d_in[6];
    const float* b2 = (const float*)d_in[7];
    float* out = (float*)d_out;

    dim3 grid(BATCH / 8);   // 4 waves/block, 2 rows/wave
    dim3 block(256);
    hipLaunchKernelGGL(mixdim_embbag_kernel, grid, block, 0, stream,
                       x, t0, t1, t2, W1, b1, W2, b2, out);
}

// Round 4
// 323.224 us; speedup vs baseline: 1.0189x; 1.0057x over previous
//
#include <hip/hip_runtime.h>
#include <hip/hip_bf16.h>

#define BATCH 16384
#define NFIELDS 26
#define FIELD_DIM 100000

// One wave handles TWO rows. Gathers are float4-vectorized across (row,field)
// pairs so each VMEM instruction fetches 1 KB of table data:
//   t0 (dim64, 256B/row): 4 pairs/instr  -> 4 instrs for 16 pairs
//   t1 (dim32, 128B/row): 8 pairs/instr  -> 2 instrs for 16 pairs
//   t2 (dim16,  64B/row): 16 pairs/instr -> 2 instrs for 20 pairs
// (was 52 scalar gather instrs/wave). Shuffle-xor trees reduce over fields;
// a small LDS transpose restores lane=dim layout for the register-resident
// projection (W1: 64x32, W2: 64x16 rows live in VGPRs, lane = output dim).
// Projection is linear -> sum embeddings first, project once per row.
// Bias enters as 8*b1[d] + 10*b2[d].

typedef float vf4 __attribute__((ext_vector_type(4)));  // clang vector: OK for nontemporal builtins

__device__ __forceinline__ vf4 ntload4(const float* p) {
    return __builtin_nontemporal_load((const vf4*)p);
}
__device__ __forceinline__ vf4 shflxor4(const vf4 v, int mask) {
    vf4 r;
    r.x = __shfl_xor(v.x, mask);
    r.y = __shfl_xor(v.y, mask);
    r.z = __shfl_xor(v.z, mask);
    r.w = __shfl_xor(v.w, mask);
    return r;
}

__global__ __launch_bounds__(256, 4) void mixdim_embbag_kernel(
    const int* __restrict__ x,
    const float* __restrict__ t0,
    const float* __restrict__ t1,
    const float* __restrict__ t2,
    const float* __restrict__ W1,
    const float* __restrict__ b1,
    const float* __restrict__ W2,
    const float* __restrict__ b2,
    float* __restrict__ out)
{
    const int lane = threadIdx.x & 63;
    const int wave = threadIdx.x >> 6;
    const int row0 = (blockIdx.x * 4 + wave) * 2;

    // Per-wave LDS: [0..127] block0 sums (2 rows x 64), [128..191] s1
    // (2 rows x 32), [192..223] s2 (2 rows x 16). 224 words/wave.
    __shared__ float lds[4 * 224];
    float* wls = &lds[wave * 224];

    // Indices: lanes 0-25 hold row0's fields, lanes 32-57 row1's.
    int xi = 0;
    {
        const int l = lane & 31;
        const int r = lane >> 5;
        if (l < NFIELDS) xi = x[(row0 + r) * NFIELDS + l];
    }

    // Projector rows -> registers (reused, L2-hot; plain loads).
    float w1r[32];
    {
        const float4* W1v = (const float4*)(W1 + lane * 32);
        #pragma unroll
        for (int i = 0; i < 8; ++i) {
            float4 v = W1v[i];
            w1r[4*i+0] = v.x; w1r[4*i+1] = v.y; w1r[4*i+2] = v.z; w1r[4*i+3] = v.w;
        }
    }
    float w2r[16];
    {
        const float4* W2v = (const float4*)(W2 + lane * 16);
        #pragma unroll
        for (int i = 0; i < 4; ++i) {
            float4 v = W2v[i];
            w2r[4*i+0] = v.x; w2r[4*i+1] = v.y; w2r[4*i+2] = v.z; w2r[4*i+3] = v.w;
        }
    }

    // ---- block 0: fields 0..7, dim 64. pair P = g*4 + (lane>>4):
    //      r = P&1 = (lane>>4)&1, j = P>>1 = g*2 + (lane>>5), chunk c = lane&15.
    vf4 a0 = {0.f, 0.f, 0.f, 0.f};
    {
        const int c = lane & 15;
        #pragma unroll
        for (int g = 0; g < 4; ++g) {
            const int P = g * 4 + (lane >> 4);
            const int r = P & 1;
            const int j = P >> 1;
            const int idx = __shfl(xi, r * 32 + j) + j * FIELD_DIM;
            a0 += ntload4(t0 + idx * 64 + c * 4);
        }
        a0 += shflxor4(a0, 32);   // reduce over j-halves (bit5)
        if (lane < 32) {
            const int r = (lane >> 4) & 1;
            *(vf4*)(wls + r * 64 + c * 4) = a0;
        }
    }

    // ---- block 1: fields 8..15, dim 32. P = g*8 + (lane>>3):
    //      r = (lane>>3)&1, j = g*4 + (lane>>4), chunk c = lane&7.
    vf4 a1 = {0.f, 0.f, 0.f, 0.f};
    {
        const int c = lane & 7;
        #pragma unroll
        for (int g = 0; g < 2; ++g) {
            const int P = g * 8 + (lane >> 3);
            const int r = P & 1;
            const int j = P >> 1;
            const int idx = __shfl(xi, r * 32 + 8 + j) + j * FIELD_DIM;
            a1 += ntload4(t1 + idx * 32 + c * 4);
        }
        a1 += shflxor4(a1, 16);   // reduce over j (bits 4,5)
        a1 += shflxor4(a1, 32);
        if (lane < 16) {
            const int r = (lane >> 3) & 1;
            *(vf4*)(wls + 128 + r * 32 + c * 4) = a1;
        }
    }

    // ---- block 2: fields 16..25, dim 16. 20 pairs, 16/instr.
    vf4 a2 = {0.f, 0.f, 0.f, 0.f};
    {
        const int c = lane & 3;
        {   // pairs 0..15: P = lane>>2, r = P&1, j = P>>1
            const int P = lane >> 2;
            const int r = P & 1;
            const int j = P >> 1;
            const int idx = __shfl(xi, r * 32 + 16 + j) + j * FIELD_DIM;
            a2 += ntload4(t2 + idx * 16 + c * 4);
        }
        {   // pairs 16..19: only lanes with P<20 load
            const int P = 16 + (lane >> 2);
            const int r = P & 1;
            const int j = P >> 1;
            const int idx = __shfl(xi, r * 32 + 16 + j) + j * FIELD_DIM;
            if (P < 20)
                a2 += ntload4(t2 + idx * 16 + c * 4);
        }
        a2 += shflxor4(a2, 8);    // reduce over j (bits 3,4,5)
        a2 += shflxor4(a2, 16);
        a2 += shflxor4(a2, 32);
        if (lane < 8) {
            const int r = (lane >> 2) & 1;
            *(vf4*)(wls + 192 + r * 16 + c * 4) = a2;
        }
    }

    __syncthreads();   // LDS stores -> reads

    // ---- projection + output: lane = output dim d ----
    float acc0 = wls[0 + lane];        // block0, row0
    float acc1 = wls[64 + lane];       // block0, row1
    #pragma unroll
    for (int k4 = 0; k4 < 8; ++k4) {   // block1: 32-dim dot, broadcast reads
        const float4 s0 = *(const float4*)(wls + 128 + k4 * 4);
        const float4 s1 = *(const float4*)(wls + 160 + k4 * 4);
        acc0 += s0.x * w1r[4*k4] + s0.y * w1r[4*k4+1] + s0.z * w1r[4*k4+2] + s0.w * w1r[4*k4+3];
        acc1 += s1.x * w1r[4*k4] + s1.y * w1r[4*k4+1] + s1.z * w1r[4*k4+2] + s1.w * w1r[4*k4+3];
    }
    #pragma unroll
    for (int k4 = 0; k4 < 4; ++k4) {   // block2: 16-dim dot
        const float4 s0 = *(const float4*)(wls + 192 + k4 * 4);
        const float4 s1 = *(const float4*)(wls + 208 + k4 * 4);
        acc0 += s0.x * w2r[4*k4] + s0.y * w2r[4*k4+1] + s0.z * w2r[4*k4+2] + s0.w * w2r[4*k4+3];
        acc1 += s1.x * w2r[4*k4] + s1.y * w2r[4*k4+1] + s1.z * w2r[4*k4+2] + s1.w * w2r[4*k4+3];
    }

    const float bias = 8.0f * b1[lane] + 10.0f * b2[lane];
    out[row0 * 64 + lane]       = acc0 + bias;
    out[(row0 + 1) * 64 + lane] = acc1 + bias;
}

extern "C" void kernel_launch(void* const* d_in, const int* in_sizes, int n_in,
                              void* d_out, int out_size, void* d_ws, size_t ws_size,
                              hipStream_t stream) {
    const int*   x  = (const int*)  d_in[0];
    const float* t0 = (const float*)d_in[1];
    const float* t1 = (const float*)d_in[2];
    const float* t2 = (const float*)d_in[3];
    const float* W1 = (const float*)d_in[4];
    const float* b1 = (const float*)d_in[5];
    const float* W2 = (const float*)d_in[6];
    const float* b2 = (const float*)d_in[7];
    float* out = (float*)d_out;

    dim3 grid(BATCH / 8);   // 4 waves/block, 2 rows/wave
    dim3 block(256);
    hipLaunchKernelGGL(mixdim_embbag_kernel, grid, block, 0, stream,
                       x, t0, t1, t2, W1, b1, W2, b2, out);
}

// Round 5
// 320.937 us; speedup vs baseline: 1.0262x; 1.0071x over previous
//
#include <hip/hip_runtime.h>
#include <hip/hip_bf16.h>

#define BATCH 16384
#define NFIELDS 26
#define FIELD_DIM 100000

// One wave handles TWO rows; lane == output dim d. Scalar per-lane gathers
// (round-4 showed gather instruction count is NOT the limiter). This round's
// single change: projector weights live in LDS (transposed) instead of 48
// VGPRs/lane, cutting register pressure so 6 waves/EU fit
// (__launch_bounds__(256,6)) -> 24 resident waves/CU vs 16, to cover gather
// latency with more outstanding requests.
//   ldsW[k*64+d]      = W1[d][k]  (k<32)  -> epilogue read lane-consecutive,
//   ldsW[2048+k*64+d] = W2[d][k]  (k<16)     conflict-free (2-way alias free)
// Projection is linear -> sum embeddings first, project once per row.
// Bias enters as 8*b1[d] + 10*b2[d]. Table gathers stay nontemporal
// (zero reuse; keep L2 for x/W/b).

__device__ __forceinline__ float ntload(const float* p) {
    return __builtin_nontemporal_load(p);
}

__global__ __launch_bounds__(256, 6) void mixdim_embbag_kernel(
    const int* __restrict__ x,
    const float* __restrict__ t0,
    const float* __restrict__ t1,
    const float* __restrict__ t2,
    const float* __restrict__ W1,
    const float* __restrict__ b1,
    const float* __restrict__ W2,
    const float* __restrict__ b2,
    float* __restrict__ out)
{
    __shared__ float ldsW[48 * 64];   // 12 KB: W1T (32x64) then W2T (16x64)

    const int tid  = threadIdx.x;
    const int lane = tid & 63;
    const int wave = tid >> 6;
    const int row0 = (blockIdx.x * 4 + wave) * 2;

    // Cooperative transposed W fill (one-time, coalesced global reads).
    #pragma unroll
    for (int i = 0; i < 8; ++i) {
        const int e = tid * 8 + i;                    // W1 has 64*32 = 2048
        ldsW[(e & 31) * 64 + (e >> 5)] = W1[e];
    }
    #pragma unroll
    for (int i = 0; i < 4; ++i) {
        const int e = tid * 4 + i;                    // W2 has 64*16 = 1024
        ldsW[2048 + (e & 15) * 64 + (e >> 4)] = W2[e];
    }

    // Indices: lanes 0-25 hold row0's 26 fields, lanes 32-57 row1's.
    int xi = 0;
    {
        const int l = lane & 31;
        const int r = lane >> 5;
        if (l < NFIELDS) xi = x[(row0 + r) * NFIELDS + l];
    }

    __syncthreads();   // ldsW ready for all waves

    float acc0 = 0.f, acc1 = 0.f;

    // ---- block 0: fields 0..7, dim 64, identity projector ----
    #pragma unroll
    for (int f = 0; f < 8; ++f) {
        const int i0 = __shfl(xi, f)      + f * FIELD_DIM;
        const int i1 = __shfl(xi, 32 + f) + f * FIELD_DIM;
        acc0 += ntload(t0 + i0 * 64 + lane);
        acc1 += ntload(t0 + i1 * 64 + lane);
    }

    // ---- block 1: fields 8..15, dim 32 (halves replicated) ----
    float s1_0 = 0.f, s1_1 = 0.f;
    {
        const int d1 = lane & 31;
        #pragma unroll
        for (int j = 0; j < 8; ++j) {
            const int i0 = __shfl(xi, 8 + j)      + j * FIELD_DIM;
            const int i1 = __shfl(xi, 32 + 8 + j) + j * FIELD_DIM;
            s1_0 += ntload(t1 + i0 * 32 + d1);
            s1_1 += ntload(t1 + i1 * 32 + d1);
        }
    }

    // ---- block 2: fields 16..25, dim 16 (quarters replicated) ----
    float s2_0 = 0.f, s2_1 = 0.f;
    {
        const int d2 = lane & 15;
        #pragma unroll
        for (int j = 0; j < 10; ++j) {
            const int i0 = __shfl(xi, 16 + j)      + j * FIELD_DIM;
            const int i1 = __shfl(xi, 32 + 16 + j) + j * FIELD_DIM;
            s2_0 += ntload(t2 + i0 * 16 + d2);
            s2_1 += ntload(t2 + i1 * 16 + d2);
        }
    }

    // ---- projections: acc[d] += sum_k s[k] * W[d][k], W from LDS ----
    #pragma unroll
    for (int k = 0; k < 32; ++k) {
        const float w = ldsW[k * 64 + lane];
        acc0 += __shfl(s1_0, k) * w;
        acc1 += __shfl(s1_1, k) * w;
    }
    #pragma unroll
    for (int k = 0; k < 16; ++k) {
        const float w = ldsW[2048 + k * 64 + lane];
        acc0 += __shfl(s2_0, k) * w;
        acc1 += __shfl(s2_1, k) * w;
    }

    // bias: 8 field-projections in block1, 10 in block2
    const float bias = 8.0f * b1[lane] + 10.0f * b2[lane];
    out[row0 * 64 + lane]       = acc0 + bias;
    out[(row0 + 1) * 64 + lane] = acc1 + bias;
}

extern "C" void kernel_launch(void* const* d_in, const int* in_sizes, int n_in,
                              void* d_out, int out_size, void* d_ws, size_t ws_size,
                              hipStream_t stream) {
    const int*   x  = (const int*)  d_in[0];
    const float* t0 = (const float*)d_in[1];
    const float* t1 = (const float*)d_in[2];
    const float* t2 = (const float*)d_in[3];
    const float* W1 = (const float*)d_in[4];
    const float* b1 = (const float*)d_in[5];
    const float* W2 = (const float*)d_in[6];
    const float* b2 = (const float*)d_in[7];
    float* out = (float*)d_out;

    dim3 grid(BATCH / 8);   // 4 waves/block, 2 rows/wave
    dim3 block(256);
    hipLaunchKernelGGL(mixdim_embbag_kernel, grid, block, 0, stream,
                       x, t0, t1, t2, W1, b1, W2, b2, out);
}